// Round 1
// baseline (234.097 us; speedup 1.0000x reference)
//
#include <hip/hip_runtime.h>
#include <math.h>

#define BATCH 512
#define NEIGH 16
#define DIM   128
#define NEG_K 4
#define M_TOT (BATCH * NEIGH)

__global__ void kg_zero(float* out) {
    if (threadIdx.x == 0) out[0] = 0.0f;
}

#define DOT4(acc, rv, vv)                    \
    acc = fmaf((rv).x, (vv).x, acc);         \
    acc = fmaf((rv).y, (vv).y, acc);         \
    acc = fmaf((rv).z, (vv).z, acc);         \
    acc = fmaf((rv).w, (vv).w, acc);

__global__ __launch_bounds__(64)
void kg_main(const float* __restrict__ mol,
             const float* __restrict__ ent,
             const float* __restrict__ rele,
             const float* __restrict__ relm,
             const int*   __restrict__ tail,
             const int*   __restrict__ rel,
             const int*   __restrict__ neg,
             float*       __restrict__ out)
{
    const int m    = blockIdx.x;
    const int lane = threadIdx.x;          // 0..63, one wave per block
    const int b    = m >> 4;               // m / NEIGH
    const int r    = rel[m];
    const int te   = tail[m];

    // Staged vectors: 0=head(self) 1=tail 2..5=neg tails
    __shared__ float sv[6][DIM];

    {
        ((float2*)sv[0])[lane] = ((const float2*)(mol + (size_t)b  * DIM))[lane];
        ((float2*)sv[1])[lane] = ((const float2*)(ent + (size_t)te * DIM))[lane];
        #pragma unroll
        for (int k = 0; k < NEG_K; ++k) {
            int nm = neg[m * NEG_K + k];   // index into M
            int nt = tail[nm];             // corrupted tail entity id
            ((float2*)sv[2 + k])[lane] = ((const float2*)(ent + (size_t)nt * DIM))[lane];
        }
    }
    __syncthreads();

    const float* Rp = relm + (size_t)r * DIM * DIM;
    // lane owns rows `lane` and `lane+64`; each R element read exactly once per block
    const float4* R0  = (const float4*)(Rp + (size_t)lane * DIM);
    const float4* R1  = (const float4*)(Rp + (size_t)(lane + 64) * DIM);
    const float4* Hv  = (const float4*)sv[0];
    const float4* Tv  = (const float4*)sv[1];
    const float4* Nv0 = (const float4*)sv[2];
    const float4* Nv1 = (const float4*)sv[3];
    const float4* Nv2 = (const float4*)sv[4];
    const float4* Nv3 = (const float4*)sv[5];

    float aH0 = 0.f, aH1 = 0.f, aT0 = 0.f, aT1 = 0.f;
    float a00 = 0.f, a01 = 0.f, a10 = 0.f, a11 = 0.f;
    float a20 = 0.f, a21 = 0.f, a30 = 0.f, a31 = 0.f;

    #pragma unroll 4
    for (int j = 0; j < DIM / 4; ++j) {
        float4 r0 = R0[j];
        float4 r1 = R1[j];
        float4 vh = Hv[j];
        float4 vt = Tv[j];
        float4 v0 = Nv0[j];
        float4 v1 = Nv1[j];
        float4 v2 = Nv2[j];
        float4 v3 = Nv3[j];
        DOT4(aH0, r0, vh); DOT4(aH1, r1, vh);
        DOT4(aT0, r0, vt); DOT4(aT1, r1, vt);
        DOT4(a00, r0, v0); DOT4(a01, r1, v0);
        DOT4(a10, r0, v1); DOT4(a11, r1, v1);
        DOT4(a20, r0, v2); DOT4(a21, r1, v2);
        DOT4(a30, r0, v3); DOT4(a31, r1, v3);
    }

    // u = Rh + rel_e for this lane's two rows
    const float re0 = rele[(size_t)r * DIM + lane];
    const float re1 = rele[(size_t)r * DIM + lane + 64];
    const float u0 = aH0 + re0;
    const float u1 = aH1 + re1;

    float d;
    float ps = 0.f, n0s = 0.f, n1s = 0.f, n2s = 0.f, n3s = 0.f;
    d = u0 - aT0; ps  += d * d;  d = u1 - aT1; ps  += d * d;
    d = u0 - a00; n0s += d * d;  d = u1 - a01; n0s += d * d;
    d = u0 - a10; n1s += d * d;  d = u1 - a11; n1s += d * d;
    d = u0 - a20; n2s += d * d;  d = u1 - a21; n2s += d * d;
    d = u0 - a30; n3s += d * d;  d = u1 - a31; n3s += d * d;

    // wave-64 reduction of the 5 partial scores
    #pragma unroll
    for (int off = 32; off > 0; off >>= 1) {
        ps  += __shfl_down(ps,  off, 64);
        n0s += __shfl_down(n0s, off, 64);
        n1s += __shfl_down(n1s, off, 64);
        n2s += __shfl_down(n2s, off, 64);
        n3s += __shfl_down(n3s, off, 64);
    }

    if (lane == 0) {
        const float neg_mean = 0.25f * (n0s + n1s + n2s + n3s);
        const float x  = neg_mean - ps;
        // sigmoid in f32; for x << 0, expf overflows to inf -> sg = 0 -> loss = -log(1e-12),
        // matching the f32 reference behavior.
        const float sg = 1.0f / (1.0f + expf(-x));
        const float l  = -logf(sg + 1e-12f);
        atomicAdd(out, l * (1.0f / (float)BATCH));
    }
}

extern "C" void kernel_launch(void* const* d_in, const int* in_sizes, int n_in,
                              void* d_out, int out_size, void* d_ws, size_t ws_size,
                              hipStream_t stream) {
    const float* mol  = (const float*)d_in[0];
    const float* ent  = (const float*)d_in[1];
    const float* rele = (const float*)d_in[2];
    const float* relm = (const float*)d_in[3];
    const int*   tail = (const int*)d_in[4];
    const int*   rel  = (const int*)d_in[5];
    const int*   neg  = (const int*)d_in[6];
    float* out = (float*)d_out;

    kg_zero<<<1, 64, 0, stream>>>(out);
    kg_main<<<M_TOT, 64, 0, stream>>>(mol, ent, rele, relm, tail, rel, neg, out);
}

// Round 3
// 132.521 us; speedup vs baseline: 1.7665x; 1.7665x over previous
//
#include <hip/hip_runtime.h>
#include <math.h>

#define BATCH  512
#define NEIGH  16
#define DIM    128
#define NEG_K  4
#define M_TOT  (BATCH * NEIGH)
#define NREL   64
#define SLICES 8          // blocks per relation
#define TPP    16         // triples per pass (one 16-wide n-tile)
#define MAXT   8          // max tiles a block can own (>= ceil(maxcnt/16)/SLICES)

typedef __attribute__((ext_vector_type(8))) short short8;
typedef __attribute__((ext_vector_type(4))) float f32x4;

// f32 -> bf16 round-to-nearest-even
static __device__ __forceinline__ unsigned short f2bf(float x) {
    unsigned u = __float_as_uint(x);
    u += 0x7FFFu + ((u >> 16) & 1u);
    return (unsigned short)(u >> 16);
}

// ---------------- kernel 1: histogram + offsets + zero ----------------
__global__ __launch_bounds__(256) void kg_prep(const int* __restrict__ rel,
                                               int* __restrict__ wsi,
                                               float* __restrict__ out) {
    __shared__ int h[NREL];
    const int tid = threadIdx.x;
    if (tid < NREL) h[tid] = 0;
    __syncthreads();
    for (int m = tid; m < M_TOT; m += 256) atomicAdd(&h[rel[m]], 1);
    __syncthreads();
    if (tid == 0) {
        int run = 0;
        for (int r = 0; r < NREL; ++r) { wsi[64 + r] = run; run += h[r]; }
        wsi[64 + NREL] = M_TOT;
        out[0] = 0.0f;
    }
    if (tid < NREL) wsi[tid] = 0;   // cursors
}

// ---------------- kernel 2: scatter ids into relation-sorted order ----------------
// ws ids layout: wsi[256 + pos*8 + f], f: 0=m 1=tail 2..5=neg-tails (6,7 unused)
__global__ __launch_bounds__(256) void kg_scatter(const int* __restrict__ tail,
                                                  const int* __restrict__ rel,
                                                  const int* __restrict__ neg,
                                                  int* __restrict__ wsi) {
    const int m = blockIdx.x * 256 + threadIdx.x;
    const int r = rel[m];
    const int pos = wsi[64 + r] + atomicAdd(&wsi[r], 1);
    const int4 nv = *(const int4*)(neg + 4 * m);
    int* ids = wsi + 256 + pos * 8;
    ids[0] = m;
    ids[1] = tail[m];
    ids[2] = tail[nv.x];
    ids[3] = tail[nv.y];
    ids[4] = tail[nv.z];
    ids[5] = tail[nv.w];
}

// ---------------- kernel 3: main ----------------
__global__ __launch_bounds__(256)
void kg_main(const float* __restrict__ mol,
             const float* __restrict__ ent,
             const float* __restrict__ rele,
             const float* __restrict__ relm,
             const int*   __restrict__ wsi,
             float*       __restrict__ out) {
    const int tid = threadIdx.x;
    const int r   = blockIdx.x >> 3;       // SLICES = 8
    const int s   = blockIdx.x & 7;

    const int off0 = wsi[64 + r];
    const int off1 = wsi[64 + r + 1];
    const int cnt  = off1 - off0;
    const int ntiles = (cnt + TPP - 1) / TPP;
    if (s >= ntiles) return;               // block-uniform
    int L = 1 + (ntiles - 1 - s) / SLICES;
    if (L > MAXT) L = MAXT;                // statistically unreachable guard

    // LDS: A = bf16 R (swizzled), B = bf16 delta panel (swizzled)
    __shared__ __align__(16) unsigned short Al[DIM * DIM];       // 32 KB
    __shared__ __align__(16) unsigned short Bl[5 * TPP * DIM];   // 20 KB
    __shared__ float reL[DIM];
    __shared__ int   idb[MAXT][TPP][8];
    __shared__ float wpart[4][TPP][5];
    __shared__ float lloss;

    if (tid == 0) lloss = 0.0f;

    // ---- stage ids for all of this block's tiles ----
    const int* wsids = wsi + 256;
    for (int idx = tid; idx < L * TPP * 8; idx += 256) {
        const int l   = idx >> 7;
        const int rem = idx & 127;
        const int tt  = rem >> 3;
        const int fld = rem & 7;
        int p = off0 + (s + l * SLICES) * TPP + tt;
        if (p > M_TOT - 1) p = M_TOT - 1;          // clamp: garbage cols discarded later
        idb[l][tt][fld] = wsids[p * 8 + fld];
    }

    // ---- stage R: fp32 global -> bf16 LDS, XOR-swizzled rows ----
    const float* Rg = relm + (size_t)r * DIM * DIM;
    #pragma unroll
    for (int it = 0; it < 16; ++it) {
        const int f   = tid + (it << 8);   // float4 index, 0..4095
        const int row = f >> 5;
        const int c4  = f & 31;
        const float4 q = *(const float4*)(Rg + row * DIM + c4 * 4);
        uint2 u;
        u.x = (unsigned)f2bf(q.x) | ((unsigned)f2bf(q.y) << 16);
        u.y = (unsigned)f2bf(q.z) | ((unsigned)f2bf(q.w) << 16);
        const int byteoff = (row << 8) + ((c4 << 3) ^ ((row & 7) << 4));
        *(uint2*)((char*)Al + byteoff) = u;
    }
    if (tid < DIM) reL[tid] = rele[r * DIM + tid];
    __syncthreads();   // idb ready for B staging (Al/reL covered by loop-entry sync)

    // ---- B staging: delta = head - tail, fp32 -> bf16, swizzled ----
    auto stageB = [&](int l) {
        #pragma unroll
        for (int it = 0; it < 20; ++it) {
            const int f   = tid + (it << 8);    // 0..5119
            const int row = f >> 6;             // 0..79 = v*16 + tt
            const int v   = row >> 4;
            const int tt  = row & 15;
            const int k2  = f & 63;             // float-pair index
            const int m0  = idb[l][tt][0];
            const int hid = m0 >> 4;            // m / NEIGH
            const int eid = idb[l][tt][1 + v];
            const float2 h2 = *(const float2*)(mol + ((size_t)hid << 7) + (k2 << 1));
            const float2 t2 = *(const float2*)(ent + ((size_t)eid << 7) + (k2 << 1));
            const unsigned pk = (unsigned)f2bf(h2.x - t2.x) |
                                ((unsigned)f2bf(h2.y - t2.y) << 16);
            const int byteoff = (row << 8) + ((k2 << 2) ^ ((row & 7) << 4));
            *(unsigned*)((char*)Bl + byteoff) = pk;
        }
    };
    stageB(0);

    const int lane = tid & 63;
    const int w    = tid >> 6;       // wave id: owns m-tiles 2w, 2w+1
    const int g    = lane >> 4;
    const int c    = lane & 15;
    const int swz  = (lane & 7) << 4;
    const f32x4 zz = {0.f, 0.f, 0.f, 0.f};

    for (int l = 0; l < L; ++l) {
        __syncthreads();   // B[l] ready; wpart free; (l==0: Al/reL ready)

        float rre[2][4];
        #pragma unroll
        for (int mt = 0; mt < 2; ++mt)
            #pragma unroll
            for (int q = 0; q < 4; ++q)
                rre[mt][q] = reL[((w * 2 + mt) << 4) + (g << 2) + q];

        f32x4 acc[2][5];
        #pragma unroll
        for (int mt = 0; mt < 2; ++mt)
            #pragma unroll
            for (int v = 0; v < 5; ++v) acc[mt][v] = zz;

        // ---- K-loop: D[m][n] = sum_k R[m][k] * delta_n[k] ----
        #pragma unroll
        for (int kk = 0; kk < 4; ++kk) {
            short8 af[2];
            #pragma unroll
            for (int mt = 0; mt < 2; ++mt) {
                const int row = ((w * 2 + mt) << 4) + c;
                af[mt] = *(const short8*)((const char*)Al + (row << 8) +
                                          (((kk << 6) + (g << 4)) ^ swz));
            }
            #pragma unroll
            for (int v = 0; v < 5; ++v) {
                const int rb = (v << 4) + c;
                const short8 bf = *(const short8*)((const char*)Bl + (rb << 8) +
                                                   (((kk << 6) + (g << 4)) ^ swz));
                acc[0][v] = __builtin_amdgcn_mfma_f32_16x16x32_bf16(af[0], bf, acc[0][v], 0, 0, 0);
                acc[1][v] = __builtin_amdgcn_mfma_f32_16x16x32_bf16(af[1], bf, acc[1][v], 0, 0, 0);
            }
        }

        // ---- epilogue: score_v(n) = sum_rows (acc + re)^2 ----
        float part[5];
        #pragma unroll
        for (int v = 0; v < 5; ++v) {
            float p2 = 0.f;
            #pragma unroll
            for (int mt = 0; mt < 2; ++mt)
                #pragma unroll
                for (int q = 0; q < 4; ++q) {
                    const float z = acc[mt][v][q] + rre[mt][q];
                    p2 = fmaf(z, z, p2);
                }
            p2 += __shfl_xor(p2, 16, 64);
            p2 += __shfl_xor(p2, 32, 64);
            part[v] = p2;
        }
        if (lane < 16) {
            #pragma unroll
            for (int v = 0; v < 5; ++v) wpart[w][lane][v] = part[v];
        }
        __syncthreads();   // wpart ready; B[l] reads done

        const int tb = (s + l * SLICES) * TPP;
        if (tid < 16 && tid < cnt - tb) {
            float pos = 0.f, n1 = 0.f, n2 = 0.f, n3 = 0.f, n4 = 0.f;
            #pragma unroll
            for (int w2 = 0; w2 < 4; ++w2) {
                pos += wpart[w2][tid][0];
                n1  += wpart[w2][tid][1];
                n2  += wpart[w2][tid][2];
                n3  += wpart[w2][tid][3];
                n4  += wpart[w2][tid][4];
            }
            const float x  = 0.25f * (n1 + n2 + n3 + n4) - pos;
            const float sg = 1.0f / (1.0f + expf(-x));
            const float lv = -logf(sg + 1e-12f);
            atomicAdd(&lloss, lv);
        }

        if (l + 1 < L) stageB(l + 1);   // overwrite B: safe, reads done
    }

    __syncthreads();
    if (tid == 0) atomicAdd(out, lloss * (1.0f / (float)BATCH));
}

extern "C" void kernel_launch(void* const* d_in, const int* in_sizes, int n_in,
                              void* d_out, int out_size, void* d_ws, size_t ws_size,
                              hipStream_t stream) {
    const float* mol  = (const float*)d_in[0];
    const float* ent  = (const float*)d_in[1];
    const float* rele = (const float*)d_in[2];
    const float* relm = (const float*)d_in[3];
    const int*   tail = (const int*)d_in[4];
    const int*   rel  = (const int*)d_in[5];
    const int*   neg  = (const int*)d_in[6];
    float* out = (float*)d_out;
    int*   wsi = (int*)d_ws;   // [0..63] cursors, [64..128] offsets, [256..] ids 8192*8

    kg_prep<<<1, 256, 0, stream>>>(rel, wsi, out);
    kg_scatter<<<M_TOT / 256, 256, 0, stream>>>(tail, rel, neg, wsi);
    kg_main<<<NREL * SLICES, 256, 0, stream>>>(mol, ent, rele, relm, wsi, out);
}

// Round 5
// 126.461 us; speedup vs baseline: 1.8511x; 1.0479x over previous
//
#include <hip/hip_runtime.h>
#include <math.h>

#define BATCH  512
#define NEIGH  16
#define DIM    128
#define NEG_K  4
#define M_TOT  (BATCH * NEIGH)
#define NREL   64
#define SLICES 8          // blocks per relation
#define TPP    16         // triples per pass (one 16-wide n-tile)
#define MAXT   2          // max tiles/block: cnt<=256 -> ntiles<=16 -> L<=2
#define BCAP   256        // bucket capacity per relation (counts ~128+-11; 256 is 11 sigma)

typedef __attribute__((ext_vector_type(8))) short short8;
typedef __attribute__((ext_vector_type(4))) float f32x4;

// f32 -> bf16 round-to-nearest-even
static __device__ __forceinline__ unsigned short f2bf(float x) {
    unsigned u = __float_as_uint(x);
    u += 0x7FFFu + ((u >> 16) & 1u);
    return (unsigned short)(u >> 16);
}

// ws layout (ints): [0..63] cursors/counts; buckets at 64 + (r*BCAP + pos)*8,
// slot fields: 0=m 1=tail 2..5=neg-tails (6,7 pad)

// ---------------- kernel 1: scatter ids into fixed-capacity relation buckets ----------------
__global__ __launch_bounds__(256) void kg_scatter(const int* __restrict__ tail,
                                                  const int* __restrict__ rel,
                                                  const int* __restrict__ neg,
                                                  int* __restrict__ wsi) {
    const int m = blockIdx.x * 256 + threadIdx.x;
    const int r = rel[m];
    const int pos = atomicAdd(&wsi[r], 1);
    if (pos >= BCAP) return;               // statistically unreachable
    const int4 nv = *(const int4*)(neg + 4 * m);
    const int4 a = { m, tail[m], tail[nv.x], tail[nv.y] };
    const int4 b = { tail[nv.z], tail[nv.w], 0, 0 };
    int* slot = wsi + 64 + ((((r << 8) + pos)) << 3);
    *(int4*)slot       = a;
    *((int4*)slot + 1) = b;
}

// ---------------- kernel 2: main (relation-batched bf16 MFMA) ----------------
__global__ __launch_bounds__(256)
void kg_main(const float* __restrict__ mol,
             const float* __restrict__ ent,
             const float* __restrict__ rele,
             const float* __restrict__ relm,
             const int*   __restrict__ wsi,
             float*       __restrict__ out) {
    const int tid = threadIdx.x;
    const int r   = blockIdx.x >> 3;       // SLICES = 8
    const int s   = blockIdx.x & 7;

    int cnt = wsi[r];
    if (cnt > BCAP) cnt = BCAP;
    const int ntiles = (cnt + TPP - 1) / TPP;
    if (s >= ntiles) return;               // block-uniform
    int L = 1 + (ntiles - 1 - s) / SLICES;
    if (L > MAXT) L = MAXT;

    // LDS: A = bf16 R (swizzled), B = bf16 delta panel (swizzled)
    __shared__ __align__(16) unsigned short Al[DIM * DIM];       // 32 KB
    __shared__ __align__(16) unsigned short Bl[5 * TPP * DIM];   // 20 KB
    __shared__ float reL[DIM];
    __shared__ int   idb[MAXT][TPP][8];
    __shared__ float wpart[4][TPP][5];
    __shared__ float lloss;

    if (tid == 0) lloss = 0.0f;

    // ---- stage ids for this block's tiles ----
    const int* bucket = wsi + 64 + ((r << 8) << 3);
    for (int idx = tid; idx < L * TPP * 8; idx += 256) {
        const int l   = idx >> 7;
        const int rem = idx & 127;
        const int tt  = rem >> 3;
        const int fld = rem & 7;
        int p = (s + l * SLICES) * TPP + tt;
        if (p >= cnt) p = 0;               // clamp: garbage cols discarded later
        idb[l][tt][fld] = bucket[p * 8 + fld];
    }

    // ---- stage R: fp32 global -> bf16 LDS, XOR-swizzled rows ----
    const float* Rg = relm + (size_t)r * DIM * DIM;
    #pragma unroll
    for (int it = 0; it < 16; ++it) {
        const int f   = tid + (it << 8);   // float4 index, 0..4095
        const int row = f >> 5;
        const int c4  = f & 31;
        const float4 q = *(const float4*)(Rg + row * DIM + c4 * 4);
        uint2 u;
        u.x = (unsigned)f2bf(q.x) | ((unsigned)f2bf(q.y) << 16);
        u.y = (unsigned)f2bf(q.z) | ((unsigned)f2bf(q.w) << 16);
        const int byteoff = (row << 8) + ((c4 << 3) ^ ((row & 7) << 4));
        *(uint2*)((char*)Al + byteoff) = u;
    }
    if (tid < DIM) reL[tid] = rele[r * DIM + tid];
    __syncthreads();   // idb/Al/reL ready

    // ---- B staging: delta = head - tail, fp32 -> bf16, swizzled ----
    auto stageB = [&](int l) {
        #pragma unroll
        for (int it = 0; it < 20; ++it) {
            const int f   = tid + (it << 8);    // 0..5119
            const int row = f >> 6;             // 0..79 = v*16 + tt
            const int v   = row >> 4;
            const int tt  = row & 15;
            const int k2  = f & 63;             // float-pair index
            const int m0  = idb[l][tt][0];
            const int hid = m0 >> 4;            // m / NEIGH
            const int eid = idb[l][tt][1 + v];
            const float2 h2 = *(const float2*)(mol + ((size_t)hid << 7) + (k2 << 1));
            const float2 t2 = *(const float2*)(ent + ((size_t)eid << 7) + (k2 << 1));
            const unsigned pk = (unsigned)f2bf(h2.x - t2.x) |
                                ((unsigned)f2bf(h2.y - t2.y) << 16);
            const int byteoff = (row << 8) + ((k2 << 2) ^ ((row & 7) << 4));
            *(unsigned*)((char*)Bl + byteoff) = pk;
        }
    };
    stageB(0);

    const int lane = tid & 63;
    const int w    = tid >> 6;       // wave id: owns m-tiles 2w, 2w+1
    const int g    = lane >> 4;
    const int c    = lane & 15;
    const int swz  = (lane & 7) << 4;
    const f32x4 zz = {0.f, 0.f, 0.f, 0.f};

    for (int l = 0; l < L; ++l) {
        __syncthreads();   // B[l] ready; wpart free

        float rre[2][4];
        #pragma unroll
        for (int mt = 0; mt < 2; ++mt)
            #pragma unroll
            for (int q = 0; q < 4; ++q)
                rre[mt][q] = reL[((w * 2 + mt) << 4) + (g << 2) + q];

        f32x4 acc[2][5];
        #pragma unroll
        for (int mt = 0; mt < 2; ++mt)
            #pragma unroll
            for (int v = 0; v < 5; ++v) acc[mt][v] = zz;

        // ---- K-loop: D[m][n] = sum_k R[m][k] * delta_n[k] ----
        #pragma unroll
        for (int kk = 0; kk < 4; ++kk) {
            short8 af[2];
            #pragma unroll
            for (int mt = 0; mt < 2; ++mt) {
                const int row = ((w * 2 + mt) << 4) + c;
                af[mt] = *(const short8*)((const char*)Al + (row << 8) +
                                          (((kk << 6) + (g << 4)) ^ swz));
            }
            #pragma unroll
            for (int v = 0; v < 5; ++v) {
                const int rb = (v << 4) + c;
                const short8 bf = *(const short8*)((const char*)Bl + (rb << 8) +
                                                   (((kk << 6) + (g << 4)) ^ swz));
                acc[0][v] = __builtin_amdgcn_mfma_f32_16x16x32_bf16(af[0], bf, acc[0][v], 0, 0, 0);
                acc[1][v] = __builtin_amdgcn_mfma_f32_16x16x32_bf16(af[1], bf, acc[1][v], 0, 0, 0);
            }
        }

        // ---- epilogue: score_v(n) = sum_rows (acc + re)^2 ----
        float part[5];
        #pragma unroll
        for (int v = 0; v < 5; ++v) {
            float p2 = 0.f;
            #pragma unroll
            for (int mt = 0; mt < 2; ++mt)
                #pragma unroll
                for (int q = 0; q < 4; ++q) {
                    const float z = acc[mt][v][q] + rre[mt][q];
                    p2 = fmaf(z, z, p2);
                }
            p2 += __shfl_xor(p2, 16, 64);
            p2 += __shfl_xor(p2, 32, 64);
            part[v] = p2;
        }
        if (lane < 16) {
            #pragma unroll
            for (int v = 0; v < 5; ++v) wpart[w][lane][v] = part[v];
        }
        __syncthreads();   // wpart ready; B[l] reads done

        const int tb = (s + l * SLICES) * TPP;
        if (tid < 16 && tid < cnt - tb) {
            float pos = 0.f, n1 = 0.f, n2 = 0.f, n3 = 0.f, n4 = 0.f;
            #pragma unroll
            for (int w2 = 0; w2 < 4; ++w2) {
                pos += wpart[w2][tid][0];
                n1  += wpart[w2][tid][1];
                n2  += wpart[w2][tid][2];
                n3  += wpart[w2][tid][3];
                n4  += wpart[w2][tid][4];
            }
            const float x  = 0.25f * (n1 + n2 + n3 + n4) - pos;
            const float sg = 1.0f / (1.0f + expf(-x));
            const float lv = -logf(sg + 1e-12f);
            atomicAdd(&lloss, lv);
        }

        if (l + 1 < L) stageB(l + 1);   // overwrite B: safe, reads done
    }

    __syncthreads();
    if (tid == 0) atomicAdd(out, lloss * (1.0f / (float)BATCH));
}

extern "C" void kernel_launch(void* const* d_in, const int* in_sizes, int n_in,
                              void* d_out, int out_size, void* d_ws, size_t ws_size,
                              hipStream_t stream) {
    const float* mol  = (const float*)d_in[0];
    const float* ent  = (const float*)d_in[1];
    const float* rele = (const float*)d_in[2];
    const float* relm = (const float*)d_in[3];
    const int*   tail = (const int*)d_in[4];
    const int*   rel  = (const int*)d_in[5];
    const int*   neg  = (const int*)d_in[6];
    float* out = (float*)d_out;
    int*   wsi = (int*)d_ws;

    // zero cursors + output (graph-capturable memset nodes)
    hipMemsetAsync(wsi, 0, NREL * sizeof(int), stream);
    hipMemsetAsync(out, 0, sizeof(float), stream);
    kg_scatter<<<M_TOT / 256, 256, 0, stream>>>(tail, rel, neg, wsi);
    kg_main<<<NREL * SLICES, 256, 0, stream>>>(mol, ent, rele, relm, wsi, out);
}

// Round 11
// 113.993 us; speedup vs baseline: 2.0536x; 1.1094x over previous
//
#include <hip/hip_runtime.h>
#include <math.h>

#define BATCH  512
#define NEIGH  16
#define DIM    128
#define NEG_K  4
#define M_TOT  (BATCH * NEIGH)
#define NREL   64
#define SLICES 8          // blocks per relation
#define TPP    16         // triples per pass (one 16-wide n-tile)
#define MAXT   2          // max tiles/block: cnt<=256 -> ntiles<=16 -> L<=2

typedef __attribute__((ext_vector_type(8))) short short8;
typedef __attribute__((ext_vector_type(4))) float f32x4;

// f32 -> bf16 round-to-nearest-even
static __device__ __forceinline__ unsigned short f2bf(float x) {
    unsigned u = __float_as_uint(x);
    u += 0x7FFFu + ((u >> 16) & 1u);
    return (unsigned short)(u >> 16);
}

// ---------------- fused kernel: per-block relation scan + batched bf16 MFMA ----------------
__global__ __launch_bounds__(256)
void kg_fused(const float* __restrict__ mol,
              const float* __restrict__ ent,
              const float* __restrict__ rele,
              const float* __restrict__ relm,
              const int*   __restrict__ tail,
              const int*   __restrict__ rel,
              const int*   __restrict__ neg,
              float*       __restrict__ out) {
    const int tid = threadIdx.x;
    const int r   = blockIdx.x >> 3;       // SLICES = 8
    const int s   = blockIdx.x & 7;

    __shared__ __align__(16) unsigned short Al[DIM * DIM];       // 32 KB, XOR-swizzled bf16 R
    __shared__ __align__(16) unsigned short Bl[5 * TPP * DIM];   // 20 KB, bf16 delta panel
    __shared__ float reL[DIM];
    __shared__ int   idb[MAXT][TPP][8];    // 0=m 1=tail 2..5=neg-tails
    __shared__ int   pfx[256];
    __shared__ float wpart[4][TPP][5];
    __shared__ float lloss;

    // zero idb (padded slots must hold safe ids) + lloss
    ((int*)idb)[tid] = 0;                  // exactly 2*16*8 = 256 ints
    if (tid == 0) lloss = 0.0f;

    // ---- scan rel[]: each thread owns 32 contiguous m's ----
    const int  base = tid << 5;
    const int4* rp  = (const int4*)(rel + base);
    unsigned mask = 0;
    int cnt_t = 0;
    #pragma unroll
    for (int i = 0; i < 8; ++i) {
        const int4 v = rp[i];
        if (v.x == r) { mask |= 1u << (4 * i + 0); ++cnt_t; }
        if (v.y == r) { mask |= 1u << (4 * i + 1); ++cnt_t; }
        if (v.z == r) { mask |= 1u << (4 * i + 2); ++cnt_t; }
        if (v.w == r) { mask |= 1u << (4 * i + 3); ++cnt_t; }
    }
    pfx[tid] = cnt_t;
    __syncthreads();
    #pragma unroll
    for (int off = 1; off < 256; off <<= 1) {
        const int v = (tid >= off) ? pfx[tid - off] : 0;
        __syncthreads();
        pfx[tid] += v;
        __syncthreads();
    }
    int cnt = pfx[255];
    if (cnt > 256) cnt = 256;              // 11-sigma guard
    const int ntiles = (cnt + TPP - 1) / TPP;
    if (s >= ntiles) return;               // block-uniform exit
    int L = 1 + (ntiles - 1 - s) / SLICES;
    if (L > MAXT) L = MAXT;

    // ---- rank-write this slice's triple ids into idb ----
    {
        int rk = pfx[tid] - cnt_t;         // exclusive prefix = global rank of first match
        unsigned mm = mask;
        while (mm) {
            const int i = __builtin_ctz(mm); mm &= mm - 1;
            const int t = rk >> 4;
            if ((t & 7) == s) {
                const int l = t >> 3;
                if (l < L) {
                    const int tt = rk & 15;
                    const int m  = base + i;
                    const int4 nv = *(const int4*)(neg + 4 * m);
                    idb[l][tt][0] = m;
                    idb[l][tt][1] = tail[m];
                    idb[l][tt][2] = tail[nv.x];
                    idb[l][tt][3] = tail[nv.y];
                    idb[l][tt][4] = tail[nv.z];
                    idb[l][tt][5] = tail[nv.w];
                }
            }
            ++rk;
        }
    }

    // ---- stage R: fp32 global -> bf16 LDS, XOR-swizzled rows ----
    const float* Rg = relm + (size_t)r * DIM * DIM;
    #pragma unroll
    for (int it = 0; it < 16; ++it) {
        const int f   = tid + (it << 8);   // float4 index, 0..4095
        const int row = f >> 5;
        const int c4  = f & 31;
        const float4 q = *(const float4*)(Rg + row * DIM + c4 * 4);
        uint2 u;
        u.x = (unsigned)f2bf(q.x) | ((unsigned)f2bf(q.y) << 16);
        u.y = (unsigned)f2bf(q.z) | ((unsigned)f2bf(q.w) << 16);
        const int byteoff = (row << 8) + ((c4 << 3) ^ ((row & 7) << 4));
        *(uint2*)((char*)Al + byteoff) = u;
    }
    if (tid < DIM) reL[tid] = rele[r * DIM + tid];
    __syncthreads();   // idb/Al/reL ready

    // ---- B staging: delta = head - tail, fp32 -> bf16, swizzled ----
    auto stageB = [&](int l) {
        #pragma unroll
        for (int it = 0; it < 20; ++it) {
            const int f   = tid + (it << 8);    // 0..5119
            const int row = f >> 6;             // 0..79 = v*16 + tt
            const int v   = row >> 4;
            const int tt  = row & 15;
            const int k2  = f & 63;             // float-pair index
            const int m0  = idb[l][tt][0];
            const int hid = m0 >> 4;            // m / NEIGH
            const int eid = idb[l][tt][1 + v];
            const float2 h2 = *(const float2*)(mol + ((size_t)hid << 7) + (k2 << 1));
            const float2 t2 = *(const float2*)(ent + ((size_t)eid << 7) + (k2 << 1));
            const unsigned pk = (unsigned)f2bf(h2.x - t2.x) |
                                ((unsigned)f2bf(h2.y - t2.y) << 16);
            const int byteoff = (row << 8) + ((k2 << 2) ^ ((row & 7) << 4));
            *(unsigned*)((char*)Bl + byteoff) = pk;
        }
    };
    stageB(0);

    const int lane = tid & 63;
    const int w    = tid >> 6;       // wave id: owns m-tiles 2w, 2w+1
    const int g    = lane >> 4;
    const int c    = lane & 15;
    const int swz  = (lane & 7) << 4;
    const f32x4 zz = {0.f, 0.f, 0.f, 0.f};

    for (int l = 0; l < L; ++l) {
        __syncthreads();   // B[l] ready; wpart free

        float rre[2][4];
        #pragma unroll
        for (int mt = 0; mt < 2; ++mt)
            #pragma unroll
            for (int q = 0; q < 4; ++q)
                rre[mt][q] = reL[((w * 2 + mt) << 4) + (g << 2) + q];

        f32x4 acc[2][5];
        #pragma unroll
        for (int mt = 0; mt < 2; ++mt)
            #pragma unroll
            for (int v = 0; v < 5; ++v) acc[mt][v] = zz;

        // ---- K-loop: D[m][n] = sum_k R[m][k] * delta_n[k] ----
        #pragma unroll
        for (int kk = 0; kk < 4; ++kk) {
            short8 af[2];
            #pragma unroll
            for (int mt = 0; mt < 2; ++mt) {
                const int row = ((w * 2 + mt) << 4) + c;
                af[mt] = *(const short8*)((const char*)Al + (row << 8) +
                                          (((kk << 6) + (g << 4)) ^ swz));
            }
            #pragma unroll
            for (int v = 0; v < 5; ++v) {
                const int rb = (v << 4) + c;
                const short8 bf = *(const short8*)((const char*)Bl + (rb << 8) +
                                                   (((kk << 6) + (g << 4)) ^ swz));
                acc[0][v] = __builtin_amdgcn_mfma_f32_16x16x32_bf16(af[0], bf, acc[0][v], 0, 0, 0);
                acc[1][v] = __builtin_amdgcn_mfma_f32_16x16x32_bf16(af[1], bf, acc[1][v], 0, 0, 0);
            }
        }

        // ---- epilogue: score_v(n) = sum_rows (acc + re)^2 ----
        float part[5];
        #pragma unroll
        for (int v = 0; v < 5; ++v) {
            float p2 = 0.f;
            #pragma unroll
            for (int mt = 0; mt < 2; ++mt)
                #pragma unroll
                for (int q = 0; q < 4; ++q) {
                    const float z = acc[mt][v][q] + rre[mt][q];
                    p2 = fmaf(z, z, p2);
                }
            p2 += __shfl_xor(p2, 16, 64);
            p2 += __shfl_xor(p2, 32, 64);
            part[v] = p2;
        }
        if (lane < 16) {
            #pragma unroll
            for (int v = 0; v < 5; ++v) wpart[w][lane][v] = part[v];
        }
        __syncthreads();   // wpart ready; B[l] reads done

        const int tb = (s + l * SLICES) * TPP;
        if (tid < 16 && tid < cnt - tb) {
            float pos = 0.f, n1 = 0.f, n2 = 0.f, n3 = 0.f, n4 = 0.f;
            #pragma unroll
            for (int w2 = 0; w2 < 4; ++w2) {
                pos += wpart[w2][tid][0];
                n1  += wpart[w2][tid][1];
                n2  += wpart[w2][tid][2];
                n3  += wpart[w2][tid][3];
                n4  += wpart[w2][tid][4];
            }
            const float x  = 0.25f * (n1 + n2 + n3 + n4) - pos;
            const float sg = 1.0f / (1.0f + expf(-x));
            const float lv = -logf(sg + 1e-12f);
            atomicAdd(&lloss, lv);
        }

        if (l + 1 < L) stageB(l + 1);   // overwrite B: safe, reads done
    }

    __syncthreads();
    if (tid == 0) atomicAdd(out, lloss * (1.0f / (float)BATCH));
}

extern "C" void kernel_launch(void* const* d_in, const int* in_sizes, int n_in,
                              void* d_out, int out_size, void* d_ws, size_t ws_size,
                              hipStream_t stream) {
    const float* mol  = (const float*)d_in[0];
    const float* ent  = (const float*)d_in[1];
    const float* rele = (const float*)d_in[2];
    const float* relm = (const float*)d_in[3];
    const int*   tail = (const int*)d_in[4];
    const int*   rel  = (const int*)d_in[5];
    const int*   neg  = (const int*)d_in[6];
    float* out = (float*)d_out;

    hipMemsetAsync(out, 0, sizeof(float), stream);
    kg_fused<<<NREL * SLICES, 256, 0, stream>>>(mol, ent, rele, relm, tail, rel, neg, out);
}